// Round 15
// baseline (797.618 us; speedup 1.0000x reference)
//
#include <hip/hip_runtime.h>
#include <hip/hip_cooperative_groups.h>

namespace cg = cooperative_groups;

#define NB 16
#define NC 256
#define NHW 784
#define NATN 16
#define NM 12544          // 16*784
#define ND 256
#define NTRI 32896        // 256*257/2
#define ATT_OUT_OFF 526336
#define SPLITK 16

typedef float f32x4 __attribute__((ext_vector_type(4)));
typedef short bf16x8 __attribute__((ext_vector_type(8)));
typedef unsigned short us8 __attribute__((ext_vector_type(8)));

static __device__ __forceinline__ unsigned short f2bf(float f) {
  unsigned int u = __float_as_uint(f);
  u = (u + 0x7FFFu + ((u >> 16) & 1u)) >> 16;   // RNE
  return (unsigned short)u;
}

#define GLD16(g, l) __builtin_amdgcn_global_load_lds(                      \
    (const __attribute__((address_space(1))) void*)(g),                    \
    (__attribute__((address_space(3))) void*)(l), 16, 0, 0)

// ---------------- att = sigmoid(raw)+eps, computed ONCE (0.8 MB) ----------------
__global__ __launch_bounds__(256)
void k_attn(const float* __restrict__ raw, float* __restrict__ att,
            float* __restrict__ out_att) {
  int i = blockIdx.x * 256 + threadIdx.x;    // 784 * 256 = 200704 exactly
  float v = raw[i];
  float a = 1.0f / (1.0f + __expf(-v)) + 1e-12f;
  att[i] = a;
  out_att[i] = a;
}

// ---------------- z = att * x (bf16) + row sums; write-bound ----------------
__global__ __launch_bounds__(256)
void k_z(const float* __restrict__ x, const float* __restrict__ att,
         unsigned short* __restrict__ z, float* __restrict__ s) {
  int bc = blockIdx.x;                 // b*256 + c
  int b  = bc >> 8;
  int t  = threadIdx.x;
  const float* xr = x + (size_t)bc * NHW;
  const float* ar = att + (size_t)b * NATN * NHW;
  unsigned short* zr = z + (size_t)bc * NM;
  float sum = 0.f;
  for (int ch = t; ch < 1568; ch += 256) {   // 1568 = 16 a * 98 chunks of 8
    int a = ch / 98;
    int hw0 = (ch - a * 98) * 8;
    float4 x0 = *(const float4*)&xr[hw0];
    float4 x1 = *(const float4*)&xr[hw0 + 4];
    const float* ap = ar + a * NHW + hw0;
    float4 a0 = *(const float4*)&ap[0];
    float4 a1 = *(const float4*)&ap[4];
    float v0 = a0.x * x0.x, v1 = a0.y * x0.y, v2 = a0.z * x0.z, v3 = a0.w * x0.w;
    float v4 = a1.x * x1.x, v5 = a1.y * x1.y, v6 = a1.z * x1.z, v7 = a1.w * x1.w;
    us8 zv;
    zv[0] = f2bf(v0); zv[1] = f2bf(v1); zv[2] = f2bf(v2); zv[3] = f2bf(v3);
    zv[4] = f2bf(v4); zv[5] = f2bf(v5); zv[6] = f2bf(v6); zv[7] = f2bf(v7);
    *(us8*)&zr[a * NHW + hw0] = zv;
    sum += v0 + v1 + v2 + v3 + v4 + v5 + v6 + v7;
  }
  for (int off = 32; off; off >>= 1) sum += __shfl_down(sum, off, 64);
  __shared__ float red[4];
  if ((t & 63) == 0) red[t >> 6] = sum;
  __syncthreads();
  if (t == 0) s[bc] = red[0] + red[1] + red[2] + red[3];
}

// ---------------- cov GEMM: P[split][b][t3] += z_tile * z_tile^T ----------------
__global__ __launch_bounds__(256)
void k_cov(const unsigned short* __restrict__ z, float* __restrict__ P) {
  int bid = blockIdx.x;
  int split = bid & 15;
  int t3 = (bid >> 4) % 3;
  int b = bid / 48;
  int tm = (t3 == 2) ? 1 : 0;
  int tn = (t3 >= 1) ? 1 : 0;

  __shared__ __align__(16) unsigned short As[128 * 64];
  __shared__ __align__(16) unsigned short Bs[128 * 64];

  int tid = threadIdx.x;
  int lane = tid & 63, w = tid >> 6;
  int wm = w >> 1, wn = w & 1;
  int fr = lane & 15, kg = lane >> 4;

  const unsigned short* zb = z + (size_t)b * NC * NM;
  int col8 = ((tid & 7) ^ ((tid >> 3) & 7)) * 8;       // source pre-swizzle
  const unsigned short* ab = zb + (size_t)(tm * 128 + (tid >> 3)) * NM + col8;
  const unsigned short* bb = zb + (size_t)(tn * 128 + (tid >> 3)) * NM + col8;

  f32x4 acc[4][4];
#pragma unroll
  for (int i = 0; i < 4; ++i)
#pragma unroll
    for (int j = 0; j < 4; ++j) acc[i][j] = f32x4{0.f, 0.f, 0.f, 0.f};

  int ktiles = 12 + (split < 4 ? 1 : 0);
  int k0 = (split * 12 + (split < 4 ? split : 4)) * 64;
  char* AsB = (char*)As + (size_t)w * 1024;
  char* BsB = (char*)Bs + (size_t)w * 1024;
  const char* Asc = (const char*)As;
  const char* Bsc = (const char*)Bs;

  for (int kt = 0; kt < ktiles; ++kt) {
    int kb = k0 + kt * 64;
#pragma unroll
    for (int r = 0; r < 4; ++r) GLD16(ab + (size_t)r * 32 * NM + kb, AsB + r * 4096);
#pragma unroll
    for (int r = 0; r < 4; ++r) GLD16(bb + (size_t)r * 32 * NM + kb, BsB + r * 4096);
    __syncthreads();
#pragma unroll
    for (int kk = 0; kk < 2; ++kk) {
      bf16x8 av[4], bv[4];
      int swz = (fr & 7) << 4;
#pragma unroll
      for (int fm = 0; fm < 4; ++fm)
        av[fm] = *(const bf16x8*)(Asc + (wm * 64 + fm * 16 + fr) * 128 + ((kk * 64 + kg * 16) ^ swz));
#pragma unroll
      for (int fn = 0; fn < 4; ++fn)
        bv[fn] = *(const bf16x8*)(Bsc + (wn * 64 + fn * 16 + fr) * 128 + ((kk * 64 + kg * 16) ^ swz));
#pragma unroll
      for (int fm = 0; fm < 4; ++fm)
#pragma unroll
        for (int fn = 0; fn < 4; ++fn)
          acc[fm][fn] = __builtin_amdgcn_mfma_f32_16x16x32_bf16(av[fm], bv[fn], acc[fm][fn], 0, 0, 0);
    }
    __syncthreads();
  }

  float* Pb = P + ((size_t)(split * NB + b) * 3 + t3) * 16384;
#pragma unroll
  for (int fm = 0; fm < 4; ++fm)
#pragma unroll
    for (int fn = 0; fn < 4; ++fn)
#pragma unroll
      for (int ri = 0; ri < 4; ++ri) {
        int row = wm * 64 + fm * 16 + kg * 4 + ri;   // tile-local
        int col = wn * 64 + fn * 16 + fr;
        Pb[row * 128 + col] = acc[fm][fn][ri];
      }
}

// ---------------- mm_tile: one 64x64 tile of C = A*B^T (B symmetric) , K=256 ----------------
// mode 0: C=A*B (bf16)   mode 1: C=1.5I-0.5*A*B (bf16)   mode 2: triu(C)*sc -> f32 out
__device__ void mm_tile(const unsigned short* __restrict__ A,
                        const unsigned short* __restrict__ Bm,
                        unsigned short* Cm, float* outp, float sc, int mode,
                        int b, int tm, int tn) {
  __shared__ __align__(16) unsigned short As[64 * 256];
  __shared__ __align__(16) unsigned short Bs[64 * 256];
  __syncthreads();   // protect LDS from previous stage's reads

  int tid = threadIdx.x, lane = tid & 63, w = tid >> 6;
  int wm = w >> 1, wn = w & 1;
  int fr = lane & 15, kg = lane >> 4;

  const unsigned short* Ab = A  + (size_t)b * 65536 + (size_t)(tm * 64) * 256;
  const unsigned short* Bb = Bm + (size_t)b * 65536 + (size_t)(tn * 64) * 256;
  int r8 = tid >> 5;                       // 0..7
  size_t srcoff = (size_t)r8 * 256 + (size_t)((tid & 31) ^ r8) * 8;
  char* AsW = (char*)As + (size_t)(w * 2) * 512;
  char* BsW = (char*)Bs + (size_t)(w * 2) * 512;
#pragma unroll
  for (int j = 0; j < 8; ++j) {
    GLD16(Ab + srcoff + (size_t)j * 8 * 256, AsW + (size_t)j * 8 * 512);
    GLD16(Bb + srcoff + (size_t)j * 8 * 256, BsW + (size_t)j * 8 * 512);
  }
  __syncthreads();

  const char* Asc = (const char*)As;
  const char* Bsc = (const char*)Bs;
  f32x4 acc[2][2];
#pragma unroll
  for (int i = 0; i < 2; ++i)
#pragma unroll
    for (int j = 0; j < 2; ++j) acc[i][j] = f32x4{0.f, 0.f, 0.f, 0.f};

  int f7 = fr & 7;
#pragma unroll
  for (int kk = 0; kk < 8; ++kk) {
    bf16x8 av[2], bv[2];
#pragma unroll
    for (int fm = 0; fm < 2; ++fm) {
      int row = wm * 32 + fm * 16 + fr;
      av[fm] = *(const bf16x8*)(Asc + row * 512 + ((((kk << 2) | kg) ^ f7) << 4));
    }
#pragma unroll
    for (int fn = 0; fn < 2; ++fn) {
      int row = wn * 32 + fn * 16 + fr;
      bv[fn] = *(const bf16x8*)(Bsc + row * 512 + ((((kk << 2) | kg) ^ f7) << 4));
    }
#pragma unroll
    for (int fm = 0; fm < 2; ++fm)
#pragma unroll
      for (int fn = 0; fn < 2; ++fn)
        acc[fm][fn] = __builtin_amdgcn_mfma_f32_16x16x32_bf16(av[fm], bv[fn], acc[fm][fn], 0, 0, 0);
  }

  if (mode == 2) {
#pragma unroll
    for (int fm = 0; fm < 2; ++fm)
#pragma unroll
      for (int fn = 0; fn < 2; ++fn)
#pragma unroll
        for (int ri = 0; ri < 4; ++ri) {
          int row = tm * 64 + wm * 32 + fm * 16 + kg * 4 + ri;
          int col = tn * 64 + wn * 32 + fn * 16 + fr;
          if (row <= col) {
            int idx = row * ND - (row * (row - 1)) / 2 + (col - row);
            outp[(size_t)b * NTRI + idx] = acc[fm][fn][ri] * sc;
          }
        }
  } else {
    unsigned short* Cb = Cm + (size_t)b * ND * ND;
#pragma unroll
    for (int fm = 0; fm < 2; ++fm)
#pragma unroll
      for (int fn = 0; fn < 2; ++fn)
#pragma unroll
        for (int ri = 0; ri < 4; ++ri) {
          int row = tm * 64 + wm * 32 + fm * 16 + kg * 4 + ri;
          int col = tn * 64 + wn * 32 + fn * 16 + fr;
          float v = acc[fm][fn][ri];
          if (mode == 1) v = (row == col ? 1.5f : 0.0f) - 0.5f * v;
          Cb[row * ND + col] = f2bf(v);
        }
  }
}

// ---------------- fused post-cov chain: asm+trace -> nrm -> anzy -> NS x5 -> triu out ----------------
// cooperative launch, grid = 256 blocks (1/CU), 256 threads
__global__ __launch_bounds__(256)
void k_fused(const float* __restrict__ P, const float* __restrict__ s,
             float* __restrict__ cov, float* __restrict__ nrm,
             float* __restrict__ ptrace,
             unsigned short* __restrict__ An, unsigned short* Yb, unsigned short* Zb,
             unsigned short* ZYb, unsigned short* Y2b, unsigned short* Z2b,
             float* __restrict__ out) {
  cg::grid_group grid = cg::this_grid();
  int bid = blockIdx.x, t = threadIdx.x;
  int b = bid >> 4, tile = bid & 15;
  int tm = tile >> 2, tn = tile & 3;
  const float invM = 1.0f / 12544.0f;

  // ---- stage 0: cov assembly (12 sub-tiles per block) + diag partial
  float diag = 0.f;
  for (int it = 0; it < 12; ++it) {
    int rem = (bid & 15) * 12 + it;      // 0..191 within batch b
    int t3 = rem >> 6;
    int loc = (rem & 63) * 256 + t;
    int row = loc >> 7, col = loc & 127;
    int tmq = (t3 == 2) ? 1 : 0;
    int tnq = (t3 >= 1) ? 1 : 0;
    int r = tmq * 128 + row, c = tnq * 128 + col;
    float g = 0.f;
#pragma unroll
    for (int sp = 0; sp < SPLITK; ++sp)
      g += P[((size_t)(sp * NB + b) * 3 + t3) * 16384 + loc];
    float v = g * invM - s[b * NC + r] * s[b * NC + c] * (invM * invM);
    cov[(size_t)b * 65536 + r * 256 + c] = v;
    if (t3 == 1) cov[(size_t)b * 65536 + c * 256 + r] = v;
    if (r == c) diag += v;
  }
  {
    for (int off = 32; off; off >>= 1) diag += __shfl_down(diag, off, 64);
    __shared__ float red[4];
    if ((t & 63) == 0) red[t >> 6] = diag;
    __syncthreads();
    if (t == 0) ptrace[bid] = red[0] + red[1] + red[2] + red[3];
  }
  __threadfence();
  grid.sync();

  // ---- stage 0b: reduce 16 partials -> nrm[b]  (blocks 0..15)
  if (bid < 16 && t < 16) {
    float v = ptrace[bid * 16 + t];
    for (int off = 8; off; off >>= 1) v += __shfl_down(v, off, 64);
    if (t == 0) nrm[bid] = v;
  }
  __threadfence();
  grid.sync();

  // ---- stage 1: An = cov/nrm ; Z0 = 1.5I - 0.5 An  (4096 elems per block)
  {
    float nb = nrm[b];
    for (int it = 0; it < 16; ++it) {
      int i = (bid << 12) + (it << 8) + t;
      int rc = i & 65535;
      int r = rc >> 8, c = rc & 255;
      float a = cov[i] / nb;
      An[i] = f2bf(a);
      Zb[i] = f2bf((r == c ? 1.5f : 0.0f) - 0.5f * a);
    }
  }
  __threadfence();
  grid.sync();

  // ---- stage 2: Y1 = An @ ZY0  (ZY0 in Zb)
  mm_tile(An, Zb, Yb, nullptr, 0.f, 0, b, tm, tn);
  __threadfence();
  grid.sync();

  unsigned short *Yc = Yb, *Zc = Zb, *Yn = Y2b, *Zn = Z2b;
  for (int it = 0; it < 3; ++it) {
    mm_tile(Zc, Yc, ZYb, nullptr, 0.f, 1, b, tm, tn);     // ZY = 1.5I - 0.5 Z@Y
    __threadfence();
    grid.sync();
    mm_tile(Yc, ZYb, Yn, nullptr, 0.f, 0, b, tm, tn);     // Y' = Y@ZY
    mm_tile(ZYb, Zc, Zn, nullptr, 0.f, 0, b, tm, tn);     // Z' = ZY@Z
    __threadfence();
    grid.sync();
    unsigned short* tp;
    tp = Yc; Yc = Yn; Yn = tp;
    tp = Zc; Zc = Zn; Zn = tp;
  }

  mm_tile(Zc, Yc, ZYb, nullptr, 0.f, 1, b, tm, tn);       // final ZY
  __threadfence();
  grid.sync();

  if (tm <= tn) {                                          // triu tiles only
    float sc = sqrtf(nrm[b]);
    mm_tile(Yc, ZYb, nullptr, out, sc, 2, b, tm, tn);
  }
}

extern "C" void kernel_launch(void* const* d_in, const int* in_sizes, int n_in,
                              void* d_out, int out_size, void* d_ws, size_t ws_size,
                              hipStream_t stream) {
  const float* x   = (const float*)d_in[0];
  const float* raw = (const float*)d_in[1];
  float* out = (float*)d_out;
  char* ws = (char*)d_ws;

  const size_t Z_OFF   = 0;
  const size_t S_OFF   = Z_OFF + (size_t)NB * NC * NM * 2;            // 102,760,448
  const size_t P_OFF   = S_OFF + (size_t)NB * NC * 4;                 // + 16,384
  const size_t COV_OFF = P_OFF + (size_t)SPLITK * NB * 3 * 16384 * 4; // + 50,331,648
  const size_t NA_OFF  = COV_OFF + (size_t)NB * ND * ND * 4;          // + 4,194,304
  const size_t PT_OFF  = NA_OFF + 64;
  const size_t AN_OFF  = PT_OFF + 1024;
  const size_t MATB    = (size_t)NB * ND * ND * 2;                    // 2,097,152
  const size_t Y_OFF   = AN_OFF + MATB;
  const size_t ZM_OFF  = Y_OFF + MATB;
  const size_t ZY_OFF  = ZM_OFF + MATB;
  const size_t Y2_OFF  = ZY_OFF + MATB;
  const size_t Z2_OFF  = Y2_OFF + MATB;
  const size_t ATT_OFF = Z2_OFF + MATB;                               // + 802,816

  unsigned short* z   = (unsigned short*)(ws + Z_OFF);
  float* ssum = (float*)(ws + S_OFF);
  float* P    = (float*)(ws + P_OFF);
  float* cov  = (float*)(ws + COV_OFF);
  float* nrm  = (float*)(ws + NA_OFF);
  float* ptrace = (float*)(ws + PT_OFF);
  unsigned short* An  = (unsigned short*)(ws + AN_OFF);
  unsigned short* Yb  = (unsigned short*)(ws + Y_OFF);
  unsigned short* Zb  = (unsigned short*)(ws + ZM_OFF);
  unsigned short* ZYb = (unsigned short*)(ws + ZY_OFF);
  unsigned short* Y2b = (unsigned short*)(ws + Y2_OFF);
  unsigned short* Z2b = (unsigned short*)(ws + Z2_OFF);
  float* att  = (float*)(ws + ATT_OFF);

  k_attn<<<784, 256, 0, stream>>>(raw, att, out + ATT_OUT_OFF);
  k_z<<<NB * NC, 256, 0, stream>>>(x, att, z, ssum);
  k_cov<<<NB * 3 * SPLITK, 256, 0, stream>>>(z, P);

  void* kargs[] = {(void*)&P, (void*)&ssum, (void*)&cov, (void*)&nrm, (void*)&ptrace,
                   (void*)&An, (void*)&Yb, (void*)&Zb, (void*)&ZYb, (void*)&Y2b,
                   (void*)&Z2b, (void*)&out};
  hipLaunchCooperativeKernel((const void*)k_fused, dim3(256), dim3(256),
                             kargs, 0, stream);
}